// Round 3
// baseline (2807.712 us; speedup 1.0000x reference)
//
#include <hip/hip_runtime.h>
#include <cstdint>
#include <cstddef>

typedef __attribute__((ext_vector_type(8))) short bf16x8;
typedef __attribute__((ext_vector_type(4))) float f32x4;

__device__ __forceinline__ unsigned short f2bf(float f) {
    union { float f; unsigned int u; } x; x.f = f;
    unsigned int u = x.u;
    unsigned int r = (u + 0x7fffu + ((u >> 16) & 1u)) >> 16;
    return (unsigned short)r;
}
__device__ __forceinline__ float sigmoidf_(float x) { return 1.0f / (1.0f + __expf(-x)); }
__device__ __forceinline__ float tanhfast_(float x) { return 2.0f / (1.0f + __expf(-2.0f * x)) - 1.0f; }

// Direct global->LDS DMA, 16 B/lane. LDS dest is wave-uniform base + lane*16;
// global src is per-lane.
__device__ __forceinline__ void gld16(const void* g, void* l) {
    __builtin_amdgcn_global_load_lds(
        (const __attribute__((address_space(1))) unsigned int*)g,
        (__attribute__((address_space(3))) unsigned int*)l, 16, 0, 0);
}

// ---------------------------------------------------------------------------
// Weight gather: wi [O][CXW][3][3], wh [O][CHW][3][3] (fp32) -> [O][ky][kx][c] bf16
// ---------------------------------------------------------------------------
__global__ void gather_w(const float* __restrict__ wi,
                         const float* __restrict__ wh,
                         unsigned short* __restrict__ dst,
                         int CXW, int CHW, int O)
{
    int C = CXW + CHW;
    int n = O * 9 * C;
    int e = blockIdx.x * 256 + threadIdx.x;
    if (e >= n) return;
    int c = e % C;
    int r = e / C;
    int kx = r % 3; r /= 3;
    int ky = r % 3;
    int o  = r / 3;
    float v = (c < CXW)
        ? wi[((size_t)o * CXW + c) * 9 + ky * 3 + kx]
        : wh[((size_t)o * CHW + (c - CXW)) * 9 + ky * 3 + kx];
    dst[e] = f2bf(v);
}

__global__ void prep_bias(const float* __restrict__ bi0, const float* __restrict__ bh0,
                          const float* __restrict__ bi1, const float* __restrict__ bh1,
                          const float* __restrict__ btp,
                          float* __restrict__ b0, float* __restrict__ b1, float* __restrict__ btf)
{
    int i = blockIdx.x * 256 + threadIdx.x;
    if (i < 512) b0[i] = bi0[i] + bh0[i];
    else if (i < 1024) { int j = i - 512; b1[j] = bi1[j] + bh1[j]; }
    else if (i < 1088) { int j = i - 1024; btf[j] = btp[j]; }
}

__global__ void zero_buf(float* __restrict__ p)
{
    p[blockIdx.x * 256 + threadIdx.x] = 0.f;
}

// ---------------------------------------------------------------------------
// Transpose [b][C][64][64] (fp32) -> channel-last [b][64][64][C], bf16 or f32.
// bf16 outputs (x, h) are written PRE-SWIZZLED: within each 64w x C row block,
// byte offset = w*C*2 + ((c*2) ^ ((w&7)<<4)).  (rule #21: both-sides swizzle)
// f32 output (c-state) keeps the plain channel-last layout.
// ---------------------------------------------------------------------------
template<bool F32OUT>
__global__ void tr_cl(const float* __restrict__ src,
                      void* __restrict__ dst,
                      int C, size_t src_off, size_t src_bstride,
                      size_t src_zstride, size_t dst_zstride)
{
    __shared__ float tile[128 * 65];
    const int h = blockIdx.x, b = blockIdx.y, z = blockIdx.z;
    const int tid = threadIdx.x;
    const float* s = src + src_off + (size_t)z * src_zstride + (size_t)b * src_bstride + h * 64;
    const int n = C * 64;
    for (int i = tid; i < n; i += 256) {
        int c = i >> 6, w = i & 63;
        tile[c * 65 + w] = s[(size_t)c * 4096 + w];
    }
    __syncthreads();
    for (int i = tid; i < n; i += 256) {
        int w = i / C, c = i % C;
        float v = tile[c * 65 + w];
        if (F32OUT) {
            size_t di = (size_t)z * dst_zstride + ((size_t)((b * 64 + h) * 64 + w)) * C + c;
            ((float*)dst)[di] = v;
        } else {
            size_t rb = ((size_t)z * dst_zstride + (size_t)((b * 64 + h) * 64) * C) * 2;
            size_t bo = rb + (size_t)w * (C * 2)
                      + (size_t)(((unsigned)(c * 2)) ^ (((unsigned)(w & 7)) << 4));
            *(unsigned short*)((char*)dst + bo) = f2bf(v);
        }
    }
}

// ---------------------------------------------------------------------------
// Fused ConvLSTM cell step, v6: one block = one (b,h) row, full M=512.
// 512 threads = 8 waves; wave ct owns out-channels ct*16..+16 for ALL 4 gates
// and ALL 64 w.  acc[4 gates][4 n-tiles] = 64 AGPRs.
//
// v6: DUAL register software-pipeline.  R2 post-mortem: per-fi cost ~2600 cyc
// == fully-serialized load latencies (compiler at 76 VGPR couldn't keep B
// fragments in flight; ds_read->wait->MFMA per nt).  Now BOTH streams are
// explicitly pipelined in registers:
//   - weights: abuf[3][4] ring, prefetch distance 2 (as v5)
//   - B-operand: bbuf[2][4] ping-pong, ds_reads of fi+1 issued before the
//     MFMA block of fi  -> compiler emits counted lgkmcnt (m97 pattern),
//     LDS latency hidden under 16 MFMAs.
// All buffer indices compile-time under full unroll (rule #20).
// ---------------------------------------------------------------------------
template<int CX, int CH>
__global__ __launch_bounds__(512, 2)
void lstm_conv(const unsigned short* __restrict__ xin,
               const unsigned short* __restrict__ hin,
               const float* __restrict__ cin,
               const unsigned short* __restrict__ wcat,
               const float* __restrict__ bias,
               const float* __restrict__ zbuf,
               unsigned short* __restrict__ hout,
               float* __restrict__ cout_)
{
    constexpr int C = CX + CH;
    constexpr int NC = C / 32;                 // c0 blocks per (ky,kx)
    constexpr int NF = 3 * NC;                 // flat iterations per ky
    constexpr int FT = 9 * NC;                 // total flat weight iterations
    constexpr int XROW = CX * 2;               // bytes per w-row, x sub-slab
    constexpr int HROW = CH * 2;               // bytes per w-row, h sub-slab
    constexpr int SLABB = 66 * (XROW + HROW);  // one buffer: [66w][x] + [66w][h]
    extern __shared__ __align__(16) char slab[];   // 2 * SLABB bytes

    const int tid = threadIdx.x;
    const int wid = tid >> 6, lane = tid & 63;
    const int quad = lane >> 4, l16 = lane & 15;
    const int ct = wid;
    const int bx = blockIdx.x;
    const int h = ((bx & 7) << 3) | (bx >> 3);   // XCD swizzle: contiguous h-band per XCD
    const int b = blockIdx.y;

    f32x4 acc[4][4];
#pragma unroll
    for (int g = 0; g < 4; ++g)
#pragma unroll
        for (int nt = 0; nt < 4; ++nt)
            acc[g][nt] = (f32x4){0.f, 0.f, 0.f, 0.f};

    const char* wr[4];
#pragma unroll
    for (int g = 0; g < 4; ++g)
        wr[g] = (const char*)(wcat + (size_t)(g * 128 + ct * 16 + l16) * (9 * C) + quad * 8);

    // per-kx read swizzle: image row w = l16 + nt*16 + kx - 1; (w&7) == (l16+kx-1)&7
    const int xv[3] = { ((l16 + 7) & 7) << 4, (l16 & 7) << 4, ((l16 + 1) & 7) << 4 };

    // weight fragment ring (distance 2); B-fragment ping-pong (distance 1).
    bf16x8 abuf[3][4];
    bf16x8 bbuf[2][4];
    auto wload = [&](int f, int s) {           // f,s constant-folded at each site
        const int off = ((f / NC) * C + (f % NC) * 32) * 2;
#pragma unroll
        for (int g = 0; g < 4; ++g)
            abuf[s][g] = *(const bf16x8*)(wr[g] + off);
    };
    auto bload = [&](const char* sx, const char* sh, int fi, int pp) {
        const int kx = fi / NC;
        const int c0 = (fi % NC) * 32;
        const bool isx = (c0 < CX);
        const char* sb = isx ? sx : sh;
        const int ROW = isx ? XROW : HROW;
        const int cc2 = (isx ? c0 : (c0 - CX)) * 2;
#pragma unroll
        for (int nt = 0; nt < 4; ++nt)
            bbuf[pp][nt] = *(const bf16x8*)(sb + (l16 + nt * 16 + kx) * ROW
                                            + ((cc2 + quad * 16) ^ xv[kx]));
    };

    auto stage = [&](int r, int buf) {
        const char* bsx;
        const char* bsh;
        if ((unsigned)r < 64u) {
            bsx = (const char*)xin + (size_t)(b * 64 + r) * (64 * XROW);
            bsh = (const char*)hin + (size_t)(b * 64 + r) * (64 * HROW);
        } else { bsx = (const char*)zbuf; bsh = (const char*)zbuf; }
        char* dx = slab + buf * SLABB + XROW;              // skip pad row w=-1
        char* dh = slab + buf * SLABB + 66 * XROW + HROW;
        constexpr int NXW = (64 * XROW) / 1024 / 8;        // 1 (CX=64) / 2 (CX=128)
        constexpr int NHW = (64 * HROW) / 1024 / 8;        // 2
#pragma unroll
        for (int k = 0; k < NXW; ++k) {
            int off = (wid * NXW + k) * 1024;
            gld16(bsx + off + lane * 16, dx + off);
        }
#pragma unroll
        for (int k = 0; k < NHW; ++k) {
            int off = (wid * NHW + k) * 1024;
            gld16(bsh + off + lane * 16, dh + off);
        }
    };

    // prologue: zero the 8 pad rows (both buffers), stage row h-1 into buf0,
    // and start the weight pipeline (f=0,1).
    {
        constexpr int PW = (2 * (XROW + HROW)) / 4;        // u32 words per buffer
        for (int i = tid; i < 2 * PW; i += 512) {
            int bu = (i >= PW) ? 1 : 0;
            int j = (i - bu * PW) * 4;
            char* base = slab + bu * SLABB;
            char* p;
            if (j < XROW)                      p = base + j;
            else if (j < 2 * XROW)             p = base + 65 * XROW + (j - XROW);
            else if (j < 2 * XROW + HROW)      p = base + 66 * XROW + (j - 2 * XROW);
            else                               p = base + 66 * XROW + 65 * HROW + (j - 2 * XROW - HROW);
            *(unsigned int*)p = 0u;
        }
    }
    stage(h - 1, 0);
    wload(0, 0);
    wload(1, 1);
    asm volatile("s_waitcnt vmcnt(0)" ::: "memory");
    __syncthreads();

#pragma unroll
    for (int ky = 0; ky < 3; ++ky) {
        // issue next row's DMA first: lands during the MFMA phase below
        if (ky == 0) stage(h, 1);
        else if (ky == 1) stage(h + 1, 0);

        const char* sx = slab + ((ky == 1) ? SLABB : 0);
        const char* sh = sx + 66 * XROW;

        bload(sx, sh, 0, 0);                   // per-ky B prologue

#pragma unroll
        for (int fi = 0; fi < NF; ++fi) {
            const int f = ky * NF + fi;
            if (fi + 1 < NF) bload(sx, sh, fi + 1, (fi + 1) & 1);   // B distance 1
            if (f + 2 < FT) wload(f + 2, (f + 2) % 3);              // A distance 2

#pragma unroll
            for (int nt = 0; nt < 4; ++nt)
#pragma unroll
                for (int g = 0; g < 4; ++g)
                    acc[g][nt] = __builtin_amdgcn_mfma_f32_16x16x32_bf16(
                        abuf[f % 3][g], bbuf[fi & 1][nt], acc[g][nt], 0, 0, 0);
        }

        if (ky < 2) {
            asm volatile("s_waitcnt vmcnt(0)" ::: "memory");  // staged buffer complete
            __syncthreads();                                  // all waves done reading cur
        }
    }

    // fused LSTM pointwise epilogue (wave-local: all 4 gates present)
    const int ch4 = ct * 16 + quad * 4;
    const unsigned hoff = ((unsigned)(ch4 * 2)) ^ (((unsigned)(l16 & 7)) << 4);  // swizzled h store
    const f32x4 bi  = *(const f32x4*)&bias[0 * 128 + ch4];
    const f32x4 bfg = *(const f32x4*)&bias[1 * 128 + ch4];
    const f32x4 bg  = *(const f32x4*)&bias[2 * 128 + ch4];
    const f32x4 bo  = *(const f32x4*)&bias[3 * 128 + ch4];
#pragma unroll
    for (int nt = 0; nt < 4; ++nt) {
        const int w = l16 + nt * 16;
        const size_t cbase = ((size_t)((b * 64 + h) * 64 + w)) * 128 + ch4;
        f32x4 cp = *(const f32x4*)&cin[cbase];
        f32x4 cy;
        union { unsigned short s[4]; uint2 v; } hp;
#pragma unroll
        for (int j = 0; j < 4; ++j) {
            float ig = sigmoidf_(acc[0][nt][j] + bi[j]);
            float fg = sigmoidf_(acc[1][nt][j] + bfg[j]);
            float gg = tanhfast_(acc[2][nt][j] + bg[j]);
            float og = sigmoidf_(acc[3][nt][j] + bo[j]);
            float cyv = fg * cp[j] + ig * gg;
            cy[j] = cyv;
            hp.s[j] = f2bf(og * tanhfast_(cyv));
        }
        *(f32x4*)&cout_[cbase] = cy;
        *(uint2*)((char*)hout + (size_t)(b * 64 + h) * (size_t)(64 * 256)
                  + (size_t)w * 256 + hoff) = hp.v;
    }
}

// ---------------------------------------------------------------------------
// Top conv v6: same dual register-pipeline (abuf[3] dist 2, bbuf[2][2] dist 1).
// 512 threads = 8 waves: ct=wid&3 (16 out-ch), nh=wid>>2 (w half), acc[2].
// ---------------------------------------------------------------------------
__global__ __launch_bounds__(512, 2)
void top_conv(const unsigned short* __restrict__ hin,
              const unsigned short* __restrict__ wtopc,
              const float* __restrict__ btf,
              const float* __restrict__ zbuf,
              float* __restrict__ out, int t)
{
    constexpr int C = 128;
    constexpr int NC = C / 32;                 // 4
    constexpr int NF = 3 * NC;                 // 12
    constexpr int FT = 9 * NC;                 // 36
    constexpr int HROW = C * 2;                // 256 B per w-row
    constexpr int SLABB = 66 * HROW;           // 16896 B per buffer
    __shared__ __align__(16) char slab[2 * SLABB];

    const int tid = threadIdx.x;
    const int wid = tid >> 6, lane = tid & 63;
    const int quad = lane >> 4, l16 = lane & 15;
    const int ct = wid & 3, nh = wid >> 2;
    const int bx = blockIdx.x;
    const int h = ((bx & 7) << 3) | (bx >> 3);
    const int b = blockIdx.y;

    f32x4 acc[2];
    acc[0] = (f32x4){0.f, 0.f, 0.f, 0.f};
    acc[1] = (f32x4){0.f, 0.f, 0.f, 0.f};

    const char* wr = (const char*)(wtopc + (size_t)(ct * 16 + l16) * (9 * C) + quad * 8);
    const int w0 = nh * 32 + l16;
    const int xv[3] = { ((l16 + 7) & 7) << 4, (l16 & 7) << 4, ((l16 + 1) & 7) << 4 };

    bf16x8 abuf[3];
    bf16x8 bbuf[2][2];
    auto wload = [&](int f, int s) {
        const int off = ((f / NC) * C + (f % NC) * 32) * 2;
        abuf[s] = *(const bf16x8*)(wr + off);
    };
    auto bload = [&](const char* sh, int fi, int pp) {
        const int kx = fi / NC;
        const int c0 = (fi % NC) * 32;
#pragma unroll
        for (int nt = 0; nt < 2; ++nt)
            bbuf[pp][nt] = *(const bf16x8*)(sh + (w0 + nt * 16 + kx) * HROW
                                            + ((c0 * 2 + quad * 16) ^ xv[kx]));
    };

    auto stage = [&](int r, int buf) {
        const char* bsh = ((unsigned)r < 64u)
            ? (const char*)hin + (size_t)(b * 64 + r) * (64 * HROW)
            : (const char*)zbuf;
        char* dh = slab + buf * SLABB + HROW;
#pragma unroll
        for (int k = 0; k < 2; ++k) {
            int off = (wid * 2 + k) * 1024;
            gld16(bsh + off + lane * 16, dh + off);
        }
    };

    {
        constexpr int PW = (2 * HROW) / 4;     // u32 words per buffer
        for (int i = tid; i < 2 * PW; i += 512) {
            int bu = (i >= PW) ? 1 : 0;
            int j = (i - bu * PW) * 4;
            char* base = slab + bu * SLABB;
            char* p = (j < HROW) ? (base + j) : (base + 65 * HROW + (j - HROW));
            *(unsigned int*)p = 0u;
        }
    }
    stage(h - 1, 0);
    wload(0, 0);
    wload(1, 1);
    asm volatile("s_waitcnt vmcnt(0)" ::: "memory");
    __syncthreads();

#pragma unroll
    for (int ky = 0; ky < 3; ++ky) {
        if (ky == 0) stage(h, 1);
        else if (ky == 1) stage(h + 1, 0);
        const char* sh = slab + ((ky == 1) ? SLABB : 0);

        bload(sh, 0, 0);

#pragma unroll
        for (int fi = 0; fi < NF; ++fi) {
            const int f = ky * NF + fi;
            if (fi + 1 < NF) bload(sh, fi + 1, (fi + 1) & 1);
            if (f + 2 < FT) wload(f + 2, (f + 2) % 3);
#pragma unroll
            for (int nt = 0; nt < 2; ++nt)
                acc[nt] = __builtin_amdgcn_mfma_f32_16x16x32_bf16(
                    abuf[f % 3], bbuf[fi & 1][nt], acc[nt], 0, 0, 0);
        }
        if (ky < 2) {
            asm volatile("s_waitcnt vmcnt(0)" ::: "memory");
            __syncthreads();
        }
    }

#pragma unroll
    for (int nt = 0; nt < 2; ++nt) {
        const int w = w0 + nt * 16;
#pragma unroll
        for (int j = 0; j < 4; ++j) {
            int o = ct * 16 + quad * 4 + j;
            out[(((size_t)(b * 10 + t) * 64 + o) * 64 + h) * 64 + w] = acc[nt][j] + btf[o];
        }
    }
}

// ---------------------------------------------------------------------------
extern "C" void kernel_launch(void* const* d_in, const int* in_sizes, int n_in,
                              void* d_out, int out_size, void* d_ws, size_t ws_size,
                              hipStream_t stream)
{
    const float* target = (const float*)d_in[0];
    const float* h0i = (const float*)d_in[1];
    const float* c0i = (const float*)d_in[2];
    const float* h1i = (const float*)d_in[3];
    const float* c1i = (const float*)d_in[4];
    const float* wi0 = (const float*)d_in[5];
    const float* bi0 = (const float*)d_in[6];
    const float* wh0 = (const float*)d_in[7];
    const float* bh0 = (const float*)d_in[8];
    const float* wi1 = (const float*)d_in[9];
    const float* bi1 = (const float*)d_in[10];
    const float* wh1 = (const float*)d_in[11];
    const float* bh1 = (const float*)d_in[12];
    const float* wtp = (const float*)d_in[13];
    const float* btp = (const float*)d_in[14];
    float* out = (float*)d_out;

    char* ws = (char*)d_ws;
    size_t off = 0;
    auto alloc = [&](size_t bytes) {
        char* p = ws + off;
        off += (bytes + 255) & ~(size_t)255;
        return (void*)p;
    };
    const size_t XSTEP = (size_t)8 * 64 * 64 * 64;          // elements per timestep slice
    unsigned short* xall  = (unsigned short*)alloc(XSTEP * 9 * 2);
    unsigned short* h0A   = (unsigned short*)alloc((size_t)8 * 64 * 64 * 128 * 2);
    unsigned short* h0B   = (unsigned short*)alloc((size_t)8 * 64 * 64 * 128 * 2);
    unsigned short* h1A   = (unsigned short*)alloc((size_t)8 * 64 * 64 * 128 * 2);
    unsigned short* h1B   = (unsigned short*)alloc((size_t)8 * 64 * 64 * 128 * 2);
    float*          c0f   = (float*)alloc((size_t)8 * 64 * 64 * 128 * 4);
    float*          c1f   = (float*)alloc((size_t)8 * 64 * 64 * 128 * 4);
    unsigned short* wcat0 = (unsigned short*)alloc((size_t)512 * 9 * 192 * 2);
    unsigned short* wcat1 = (unsigned short*)alloc((size_t)512 * 9 * 256 * 2);
    unsigned short* wtc   = (unsigned short*)alloc((size_t)64 * 9 * 128 * 2);
    float*          b0s   = (float*)alloc(512 * 4);
    float*          b1s   = (float*)alloc(512 * 4);
    float*          btf   = (float*)alloc(64 * 4);
    float*          zpg   = (float*)alloc(16384);           // zero page for OOB staging

    constexpr int LDS_L0 = 2 * 66 * ((64 + 128) * 2);       // 50688
    constexpr int LDS_L1 = 2 * 66 * ((128 + 128) * 2);      // 67584
    hipFuncSetAttribute(reinterpret_cast<const void*>(lstm_conv<64, 128>),
                        hipFuncAttributeMaxDynamicSharedMemorySize, LDS_L0);
    hipFuncSetAttribute(reinterpret_cast<const void*>(lstm_conv<128, 128>),
                        hipFuncAttributeMaxDynamicSharedMemorySize, LDS_L1);

    gather_w<<<(512 * 9 * 192 + 255) / 256, 256, 0, stream>>>(wi0, wh0, wcat0, 64, 128, 512);
    gather_w<<<(512 * 9 * 256 + 255) / 256, 256, 0, stream>>>(wi1, wh1, wcat1, 128, 128, 512);
    gather_w<<<(64 * 9 * 128 + 255) / 256, 256, 0, stream>>>(wtp, wtp, wtc, 128, 0, 64);
    prep_bias<<<5, 256, 0, stream>>>(bi0, bh0, bi1, bh1, btp, b0s, b1s, btf);
    zero_buf<<<16, 256, 0, stream>>>(zpg);

    // initial states -> channel-last (bf16 paths pre-swizzled)
    tr_cl<false><<<dim3(64, 8, 1), 256, 0, stream>>>(h0i, h0A, 128, 0, (size_t)128 * 4096, 0, 0);
    tr_cl<false><<<dim3(64, 8, 1), 256, 0, stream>>>(h1i, h1A, 128, 0, (size_t)128 * 4096, 0, 0);
    tr_cl<true ><<<dim3(64, 8, 1), 256, 0, stream>>>(c0i, c0f, 128, 0, (size_t)128 * 4096, 0, 0);
    tr_cl<true ><<<dim3(64, 8, 1), 256, 0, stream>>>(c1i, c1f, 128, 0, (size_t)128 * 4096, 0, 0);
    // all 9 input timesteps -> channel-last, one dispatch
    tr_cl<false><<<dim3(64, 8, 9), 256, 0, stream>>>(target, xall, 64,
                                                     0, (size_t)10 * 64 * 4096,
                                                     (size_t)64 * 4096, XSTEP);

    top_conv<<<dim3(64, 8), 512, 0, stream>>>(h1A, wtc, btf, zpg, out, 0);

    unsigned short* h0p[2] = { h0A, h0B };
    unsigned short* h1p[2] = { h1A, h1B };
    for (int t = 0; t < 9; ++t) {
        int p = t & 1;
        lstm_conv<64, 128><<<dim3(64, 8), 512, LDS_L0, stream>>>(
            xall + (size_t)t * XSTEP, h0p[p], c0f, wcat0, b0s, zpg, h0p[1 - p], c0f);
        lstm_conv<128, 128><<<dim3(64, 8), 512, LDS_L1, stream>>>(
            h0p[1 - p], h1p[p], c1f, wcat1, b1s, zpg, h1p[1 - p], c1f);
        top_conv<<<dim3(64, 8), 512, 0, stream>>>(h1p[1 - p], wtc, btf, zpg, out, t + 1);
    }
}

// Round 4
// 2753.544 us; speedup vs baseline: 1.0197x; 1.0197x over previous
//
#include <hip/hip_runtime.h>
#include <cstdint>
#include <cstddef>

typedef __attribute__((ext_vector_type(8))) short bf16x8;
typedef __attribute__((ext_vector_type(4))) float f32x4;

__device__ __forceinline__ unsigned short f2bf(float f) {
    union { float f; unsigned int u; } x; x.f = f;
    unsigned int u = x.u;
    unsigned int r = (u + 0x7fffu + ((u >> 16) & 1u)) >> 16;
    return (unsigned short)r;
}
__device__ __forceinline__ float sigmoidf_(float x) { return 1.0f / (1.0f + __expf(-x)); }
__device__ __forceinline__ float tanhfast_(float x) { return 2.0f / (1.0f + __expf(-2.0f * x)) - 1.0f; }

// Direct global->LDS DMA, 16 B/lane. LDS dest is wave-uniform base + lane*16;
// global src is per-lane.
__device__ __forceinline__ void gld16(const void* g, void* l) {
    __builtin_amdgcn_global_load_lds(
        (const __attribute__((address_space(1))) unsigned int*)g,
        (__attribute__((address_space(3))) unsigned int*)l, 16, 0, 0);
}

// ---------------------------------------------------------------------------
// Weight gather: wi [O][CXW][3][3], wh [O][CHW][3][3] (fp32) -> [O][ky][kx][c] bf16
// ---------------------------------------------------------------------------
__global__ void gather_w(const float* __restrict__ wi,
                         const float* __restrict__ wh,
                         unsigned short* __restrict__ dst,
                         int CXW, int CHW, int O)
{
    int C = CXW + CHW;
    int n = O * 9 * C;
    int e = blockIdx.x * 256 + threadIdx.x;
    if (e >= n) return;
    int c = e % C;
    int r = e / C;
    int kx = r % 3; r /= 3;
    int ky = r % 3;
    int o  = r / 3;
    float v = (c < CXW)
        ? wi[((size_t)o * CXW + c) * 9 + ky * 3 + kx]
        : wh[((size_t)o * CHW + (c - CXW)) * 9 + ky * 3 + kx];
    dst[e] = f2bf(v);
}

__global__ void prep_bias(const float* __restrict__ bi0, const float* __restrict__ bh0,
                          const float* __restrict__ bi1, const float* __restrict__ bh1,
                          const float* __restrict__ btp,
                          float* __restrict__ b0, float* __restrict__ b1, float* __restrict__ btf)
{
    int i = blockIdx.x * 256 + threadIdx.x;
    if (i < 512) b0[i] = bi0[i] + bh0[i];
    else if (i < 1024) { int j = i - 512; b1[j] = bi1[j] + bh1[j]; }
    else if (i < 1088) { int j = i - 1024; btf[j] = btp[j]; }
}

__global__ void zero_buf(float* __restrict__ p)
{
    p[blockIdx.x * 256 + threadIdx.x] = 0.f;
}

// ---------------------------------------------------------------------------
// Transpose [b][C][64][64] (fp32) -> channel-last [b][64][64][C], bf16 or f32.
// bf16 outputs (x, h) are written PRE-SWIZZLED: within each 64w x C row block,
// byte offset = w*C*2 + ((c*2) ^ ((w&7)<<4)).  (rule #21: both-sides swizzle)
// f32 output (c-state) keeps the plain channel-last layout.
// ---------------------------------------------------------------------------
template<bool F32OUT>
__global__ void tr_cl(const float* __restrict__ src,
                      void* __restrict__ dst,
                      int C, size_t src_off, size_t src_bstride,
                      size_t src_zstride, size_t dst_zstride)
{
    __shared__ float tile[128 * 65];
    const int h = blockIdx.x, b = blockIdx.y, z = blockIdx.z;
    const int tid = threadIdx.x;
    const float* s = src + src_off + (size_t)z * src_zstride + (size_t)b * src_bstride + h * 64;
    const int n = C * 64;
    for (int i = tid; i < n; i += 256) {
        int c = i >> 6, w = i & 63;
        tile[c * 65 + w] = s[(size_t)c * 4096 + w];
    }
    __syncthreads();
    for (int i = tid; i < n; i += 256) {
        int w = i / C, c = i % C;
        float v = tile[c * 65 + w];
        if (F32OUT) {
            size_t di = (size_t)z * dst_zstride + ((size_t)((b * 64 + h) * 64 + w)) * C + c;
            ((float*)dst)[di] = v;
        } else {
            size_t rb = ((size_t)z * dst_zstride + (size_t)((b * 64 + h) * 64) * C) * 2;
            size_t bo = rb + (size_t)w * (C * 2)
                      + (size_t)(((unsigned)(c * 2)) ^ (((unsigned)(w & 7)) << 4));
            *(unsigned short*)((char*)dst + bo) = f2bf(v);
        }
    }
}

// ---------------------------------------------------------------------------
// Fused ConvLSTM cell step, v7: one block = one (b,h) row, full M=512.
// 512 threads = 8 waves; wave ct owns out-channels ct*16..+16 for ALL 4 gates
// and ALL 64 w.  acc[4 gates][4 n-tiles] = 64 AGPRs.
//
// v7: PHASE DISCIPLINE (T3+T4+T5, m196/m218/m218b).  R1-R3 showed ILP<->TLP
// is a closed trade at this structure (every added pipeline reg dropped
// occupancy 2->1 block/CU; dur pinned at ~160us, all pipes <23%).  The proven
// lever for this regime is the per-phase lockstep: per fi,
//   {issue B ds_reads(fi+1) + A loads(f+2)} | sched_barrier | raw s_barrier |
//   sched_barrier | setprio(1) 16xMFMA setprio(0)
// so each SIMD's waves alternate {load-issue}/{MFMA} roles, and ky boundaries
// use COUNTED vmcnt(8) (retire staging DMAs, keep the 8 in-flight weight
// loads alive across the barrier) instead of a vmcnt(0) drain.
// ---------------------------------------------------------------------------
template<int CX, int CH>
__global__ __launch_bounds__(512, 2)
void lstm_conv(const unsigned short* __restrict__ xin,
               const unsigned short* __restrict__ hin,
               const float* __restrict__ cin,
               const unsigned short* __restrict__ wcat,
               const float* __restrict__ bias,
               const float* __restrict__ zbuf,
               unsigned short* __restrict__ hout,
               float* __restrict__ cout_)
{
    constexpr int C = CX + CH;
    constexpr int NC = C / 32;                 // c0 blocks per (ky,kx)
    constexpr int NF = 3 * NC;                 // flat iterations per ky
    constexpr int FT = 9 * NC;                 // total flat weight iterations
    constexpr int XROW = CX * 2;               // bytes per w-row, x sub-slab
    constexpr int HROW = CH * 2;               // bytes per w-row, h sub-slab
    constexpr int SLABB = 66 * (XROW + HROW);  // one buffer: [66w][x] + [66w][h]
    extern __shared__ __align__(16) char slab[];   // 2 * SLABB bytes

    const int tid = threadIdx.x;
    const int wid = tid >> 6, lane = tid & 63;
    const int quad = lane >> 4, l16 = lane & 15;
    const int ct = wid;
    const int bx = blockIdx.x;
    const int h = ((bx & 7) << 3) | (bx >> 3);   // XCD swizzle: contiguous h-band per XCD
    const int b = blockIdx.y;

    f32x4 acc[4][4];
#pragma unroll
    for (int g = 0; g < 4; ++g)
#pragma unroll
        for (int nt = 0; nt < 4; ++nt)
            acc[g][nt] = (f32x4){0.f, 0.f, 0.f, 0.f};

    const char* wr[4];
#pragma unroll
    for (int g = 0; g < 4; ++g)
        wr[g] = (const char*)(wcat + (size_t)(g * 128 + ct * 16 + l16) * (9 * C) + quad * 8);

    // per-kx read swizzle: image row w = l16 + nt*16 + kx - 1; (w&7) == (l16+kx-1)&7
    const int xv[3] = { ((l16 + 7) & 7) << 4, (l16 & 7) << 4, ((l16 + 1) & 7) << 4 };

    // weight fragment ring (distance 2); B-fragment ping-pong (distance 1).
    bf16x8 abuf[3][4];
    bf16x8 bbuf[2][4];
    auto wload = [&](int f, int s) {           // f,s constant-folded at each site
        const int off = ((f / NC) * C + (f % NC) * 32) * 2;
#pragma unroll
        for (int g = 0; g < 4; ++g)
            abuf[s][g] = *(const bf16x8*)(wr[g] + off);
    };
    auto bload = [&](const char* sx, const char* sh, int fi, int pp) {
        const int kx = fi / NC;
        const int c0 = (fi % NC) * 32;
        const bool isx = (c0 < CX);
        const char* sb = isx ? sx : sh;
        const int ROW = isx ? XROW : HROW;
        const int cc2 = (isx ? c0 : (c0 - CX)) * 2;
#pragma unroll
        for (int nt = 0; nt < 4; ++nt)
            bbuf[pp][nt] = *(const bf16x8*)(sb + (l16 + nt * 16 + kx) * ROW
                                            + ((cc2 + quad * 16) ^ xv[kx]));
    };

    auto stage = [&](int r, int buf) {
        const char* bsx;
        const char* bsh;
        if ((unsigned)r < 64u) {
            bsx = (const char*)xin + (size_t)(b * 64 + r) * (64 * XROW);
            bsh = (const char*)hin + (size_t)(b * 64 + r) * (64 * HROW);
        } else { bsx = (const char*)zbuf; bsh = (const char*)zbuf; }
        char* dx = slab + buf * SLABB + XROW;              // skip pad row w=-1
        char* dh = slab + buf * SLABB + 66 * XROW + HROW;
        constexpr int NXW = (64 * XROW) / 1024 / 8;        // 1 (CX=64) / 2 (CX=128)
        constexpr int NHW = (64 * HROW) / 1024 / 8;        // 2
#pragma unroll
        for (int k = 0; k < NXW; ++k) {
            int off = (wid * NXW + k) * 1024;
            gld16(bsx + off + lane * 16, dx + off);
        }
#pragma unroll
        for (int k = 0; k < NHW; ++k) {
            int off = (wid * NHW + k) * 1024;
            gld16(bsh + off + lane * 16, dh + off);
        }
    };

    // prologue: zero the 8 pad rows (both buffers), stage row h-1 into buf0,
    // and start the weight pipeline (f=0,1).  One-time full drain is fine.
    {
        constexpr int PW = (2 * (XROW + HROW)) / 4;        // u32 words per buffer
        for (int i = tid; i < 2 * PW; i += 512) {
            int bu = (i >= PW) ? 1 : 0;
            int j = (i - bu * PW) * 4;
            char* base = slab + bu * SLABB;
            char* p;
            if (j < XROW)                      p = base + j;
            else if (j < 2 * XROW)             p = base + 65 * XROW + (j - XROW);
            else if (j < 2 * XROW + HROW)      p = base + 66 * XROW + (j - 2 * XROW);
            else                               p = base + 66 * XROW + 65 * HROW + (j - 2 * XROW - HROW);
            *(unsigned int*)p = 0u;
        }
    }
    stage(h - 1, 0);
    wload(0, 0);
    wload(1, 1);
    __syncthreads();

#pragma unroll
    for (int ky = 0; ky < 3; ++ky) {
        // issue next row's DMA first: lands during the MFMA phases below
        if (ky == 0) stage(h, 1);
        else if (ky == 1) stage(h + 1, 0);

        const char* sx = slab + ((ky == 1) ? SLABB : 0);
        const char* sh = sx + 66 * XROW;

        bload(sx, sh, 0, 0);                   // per-ky B prologue

#pragma unroll
        for (int fi = 0; fi < NF; ++fi) {
            const int f = ky * NF + fi;
            // ---- load-issue half of the phase ----
            if (fi + 1 < NF) bload(sx, sh, fi + 1, (fi + 1) & 1);   // B distance 1
            if (f + 2 < FT) wload(f + 2, (f + 2) % 3);              // A distance 2

            // ---- phase alignment: loads pinned above, MFMA below ----
            __builtin_amdgcn_sched_barrier(0);
            __builtin_amdgcn_s_barrier();
            __builtin_amdgcn_sched_barrier(0);

            __builtin_amdgcn_s_setprio(1);
#pragma unroll
            for (int nt = 0; nt < 4; ++nt)
#pragma unroll
                for (int g = 0; g < 4; ++g)
                    acc[g][nt] = __builtin_amdgcn_mfma_f32_16x16x32_bf16(
                        abuf[f % 3][g], bbuf[fi & 1][nt], acc[g][nt], 0, 0, 0);
            __builtin_amdgcn_s_setprio(0);
        }

        if (ky < 2) {
            // counted: retire staging DMAs (oldest), keep the <=8 in-flight
            // weight loads alive across the barrier (T4: never drain to 0).
            asm volatile("s_waitcnt vmcnt(8)" ::: "memory");
            __builtin_amdgcn_s_barrier();
            __builtin_amdgcn_sched_barrier(0);
        }
    }

    // fused LSTM pointwise epilogue (wave-local: all 4 gates present)
    const int ch4 = ct * 16 + quad * 4;
    const unsigned hoff = ((unsigned)(ch4 * 2)) ^ (((unsigned)(l16 & 7)) << 4);  // swizzled h store
    const f32x4 bi  = *(const f32x4*)&bias[0 * 128 + ch4];
    const f32x4 bfg = *(const f32x4*)&bias[1 * 128 + ch4];
    const f32x4 bg  = *(const f32x4*)&bias[2 * 128 + ch4];
    const f32x4 bo  = *(const f32x4*)&bias[3 * 128 + ch4];
#pragma unroll
    for (int nt = 0; nt < 4; ++nt) {
        const int w = l16 + nt * 16;
        const size_t cbase = ((size_t)((b * 64 + h) * 64 + w)) * 128 + ch4;
        f32x4 cp = *(const f32x4*)&cin[cbase];
        f32x4 cy;
        union { unsigned short s[4]; uint2 v; } hp;
#pragma unroll
        for (int j = 0; j < 4; ++j) {
            float ig = sigmoidf_(acc[0][nt][j] + bi[j]);
            float fg = sigmoidf_(acc[1][nt][j] + bfg[j]);
            float gg = tanhfast_(acc[2][nt][j] + bg[j]);
            float og = sigmoidf_(acc[3][nt][j] + bo[j]);
            float cyv = fg * cp[j] + ig * gg;
            cy[j] = cyv;
            hp.s[j] = f2bf(og * tanhfast_(cyv));
        }
        *(f32x4*)&cout_[cbase] = cy;
        *(uint2*)((char*)hout + (size_t)(b * 64 + h) * (size_t)(64 * 256)
                  + (size_t)w * 256 + hoff) = hp.v;
    }
}

// ---------------------------------------------------------------------------
// Top conv v7: same phase discipline (barrier+setprio per fi, counted vmcnt).
// 512 threads = 8 waves: ct=wid&3 (16 out-ch), nh=wid>>2 (w half), acc[2].
// ---------------------------------------------------------------------------
__global__ __launch_bounds__(512, 2)
void top_conv(const unsigned short* __restrict__ hin,
              const unsigned short* __restrict__ wtopc,
              const float* __restrict__ btf,
              const float* __restrict__ zbuf,
              float* __restrict__ out, int t)
{
    constexpr int C = 128;
    constexpr int NC = C / 32;                 // 4
    constexpr int NF = 3 * NC;                 // 12
    constexpr int FT = 9 * NC;                 // 36
    constexpr int HROW = C * 2;                // 256 B per w-row
    constexpr int SLABB = 66 * HROW;           // 16896 B per buffer
    __shared__ __align__(16) char slab[2 * SLABB];

    const int tid = threadIdx.x;
    const int wid = tid >> 6, lane = tid & 63;
    const int quad = lane >> 4, l16 = lane & 15;
    const int ct = wid & 3, nh = wid >> 2;
    const int bx = blockIdx.x;
    const int h = ((bx & 7) << 3) | (bx >> 3);
    const int b = blockIdx.y;

    f32x4 acc[2];
    acc[0] = (f32x4){0.f, 0.f, 0.f, 0.f};
    acc[1] = (f32x4){0.f, 0.f, 0.f, 0.f};

    const char* wr = (const char*)(wtopc + (size_t)(ct * 16 + l16) * (9 * C) + quad * 8);
    const int w0 = nh * 32 + l16;
    const int xv[3] = { ((l16 + 7) & 7) << 4, (l16 & 7) << 4, ((l16 + 1) & 7) << 4 };

    bf16x8 abuf[3];
    bf16x8 bbuf[2][2];
    auto wload = [&](int f, int s) {
        const int off = ((f / NC) * C + (f % NC) * 32) * 2;
        abuf[s] = *(const bf16x8*)(wr + off);
    };
    auto bload = [&](const char* sh, int fi, int pp) {
        const int kx = fi / NC;
        const int c0 = (fi % NC) * 32;
#pragma unroll
        for (int nt = 0; nt < 2; ++nt)
            bbuf[pp][nt] = *(const bf16x8*)(sh + (w0 + nt * 16 + kx) * HROW
                                            + ((c0 * 2 + quad * 16) ^ xv[kx]));
    };

    auto stage = [&](int r, int buf) {
        const char* bsh = ((unsigned)r < 64u)
            ? (const char*)hin + (size_t)(b * 64 + r) * (64 * HROW)
            : (const char*)zbuf;
        char* dh = slab + buf * SLABB + HROW;
#pragma unroll
        for (int k = 0; k < 2; ++k) {
            int off = (wid * 2 + k) * 1024;
            gld16(bsh + off + lane * 16, dh + off);
        }
    };

    {
        constexpr int PW = (2 * HROW) / 4;     // u32 words per buffer
        for (int i = tid; i < 2 * PW; i += 512) {
            int bu = (i >= PW) ? 1 : 0;
            int j = (i - bu * PW) * 4;
            char* base = slab + bu * SLABB;
            char* p = (j < HROW) ? (base + j) : (base + 65 * HROW + (j - HROW));
            *(unsigned int*)p = 0u;
        }
    }
    stage(h - 1, 0);
    wload(0, 0);
    wload(1, 1);
    __syncthreads();

#pragma unroll
    for (int ky = 0; ky < 3; ++ky) {
        if (ky == 0) stage(h, 1);
        else if (ky == 1) stage(h + 1, 0);
        const char* sh = slab + ((ky == 1) ? SLABB : 0);

        bload(sh, 0, 0);

#pragma unroll
        for (int fi = 0; fi < NF; ++fi) {
            const int f = ky * NF + fi;
            if (fi + 1 < NF) bload(sh, fi + 1, (fi + 1) & 1);
            if (f + 2 < FT) wload(f + 2, (f + 2) % 3);

            __builtin_amdgcn_sched_barrier(0);
            __builtin_amdgcn_s_barrier();
            __builtin_amdgcn_sched_barrier(0);

            __builtin_amdgcn_s_setprio(1);
#pragma unroll
            for (int nt = 0; nt < 2; ++nt)
                acc[nt] = __builtin_amdgcn_mfma_f32_16x16x32_bf16(
                    abuf[f % 3], bbuf[fi & 1][nt], acc[nt], 0, 0, 0);
            __builtin_amdgcn_s_setprio(0);
        }
        if (ky < 2) {
            asm volatile("s_waitcnt vmcnt(2)" ::: "memory");
            __builtin_amdgcn_s_barrier();
            __builtin_amdgcn_sched_barrier(0);
        }
    }

#pragma unroll
    for (int nt = 0; nt < 2; ++nt) {
        const int w = w0 + nt * 16;
#pragma unroll
        for (int j = 0; j < 4; ++j) {
            int o = ct * 16 + quad * 4 + j;
            out[(((size_t)(b * 10 + t) * 64 + o) * 64 + h) * 64 + w] = acc[nt][j] + btf[o];
        }
    }
}

// ---------------------------------------------------------------------------
extern "C" void kernel_launch(void* const* d_in, const int* in_sizes, int n_in,
                              void* d_out, int out_size, void* d_ws, size_t ws_size,
                              hipStream_t stream)
{
    const float* target = (const float*)d_in[0];
    const float* h0i = (const float*)d_in[1];
    const float* c0i = (const float*)d_in[2];
    const float* h1i = (const float*)d_in[3];
    const float* c1i = (const float*)d_in[4];
    const float* wi0 = (const float*)d_in[5];
    const float* bi0 = (const float*)d_in[6];
    const float* wh0 = (const float*)d_in[7];
    const float* bh0 = (const float*)d_in[8];
    const float* wi1 = (const float*)d_in[9];
    const float* bi1 = (const float*)d_in[10];
    const float* wh1 = (const float*)d_in[11];
    const float* bh1 = (const float*)d_in[12];
    const float* wtp = (const float*)d_in[13];
    const float* btp = (const float*)d_in[14];
    float* out = (float*)d_out;

    char* ws = (char*)d_ws;
    size_t off = 0;
    auto alloc = [&](size_t bytes) {
        char* p = ws + off;
        off += (bytes + 255) & ~(size_t)255;
        return (void*)p;
    };
    const size_t XSTEP = (size_t)8 * 64 * 64 * 64;          // elements per timestep slice
    unsigned short* xall  = (unsigned short*)alloc(XSTEP * 9 * 2);
    unsigned short* h0A   = (unsigned short*)alloc((size_t)8 * 64 * 64 * 128 * 2);
    unsigned short* h0B   = (unsigned short*)alloc((size_t)8 * 64 * 64 * 128 * 2);
    unsigned short* h1A   = (unsigned short*)alloc((size_t)8 * 64 * 64 * 128 * 2);
    unsigned short* h1B   = (unsigned short*)alloc((size_t)8 * 64 * 64 * 128 * 2);
    float*          c0f   = (float*)alloc((size_t)8 * 64 * 64 * 128 * 4);
    float*          c1f   = (float*)alloc((size_t)8 * 64 * 64 * 128 * 4);
    unsigned short* wcat0 = (unsigned short*)alloc((size_t)512 * 9 * 192 * 2);
    unsigned short* wcat1 = (unsigned short*)alloc((size_t)512 * 9 * 256 * 2);
    unsigned short* wtc   = (unsigned short*)alloc((size_t)64 * 9 * 128 * 2);
    float*          b0s   = (float*)alloc(512 * 4);
    float*          b1s   = (float*)alloc(512 * 4);
    float*          btf   = (float*)alloc(64 * 4);
    float*          zpg   = (float*)alloc(16384);           // zero page for OOB staging

    constexpr int LDS_L0 = 2 * 66 * ((64 + 128) * 2);       // 50688
    constexpr int LDS_L1 = 2 * 66 * ((128 + 128) * 2);      // 67584
    hipFuncSetAttribute(reinterpret_cast<const void*>(lstm_conv<64, 128>),
                        hipFuncAttributeMaxDynamicSharedMemorySize, LDS_L0);
    hipFuncSetAttribute(reinterpret_cast<const void*>(lstm_conv<128, 128>),
                        hipFuncAttributeMaxDynamicSharedMemorySize, LDS_L1);

    gather_w<<<(512 * 9 * 192 + 255) / 256, 256, 0, stream>>>(wi0, wh0, wcat0, 64, 128, 512);
    gather_w<<<(512 * 9 * 256 + 255) / 256, 256, 0, stream>>>(wi1, wh1, wcat1, 128, 128, 512);
    gather_w<<<(64 * 9 * 128 + 255) / 256, 256, 0, stream>>>(wtp, wtp, wtc, 128, 0, 64);
    prep_bias<<<5, 256, 0, stream>>>(bi0, bh0, bi1, bh1, btp, b0s, b1s, btf);
    zero_buf<<<16, 256, 0, stream>>>(zpg);

    // initial states -> channel-last (bf16 paths pre-swizzled)
    tr_cl<false><<<dim3(64, 8, 1), 256, 0, stream>>>(h0i, h0A, 128, 0, (size_t)128 * 4096, 0, 0);
    tr_cl<false><<<dim3(64, 8, 1), 256, 0, stream>>>(h1i, h1A, 128, 0, (size_t)128 * 4096, 0, 0);
    tr_cl<true ><<<dim3(64, 8, 1), 256, 0, stream>>>(c0i, c0f, 128, 0, (size_t)128 * 4096, 0, 0);
    tr_cl<true ><<<dim3(64, 8, 1), 256, 0, stream>>>(c1i, c1f, 128, 0, (size_t)128 * 4096, 0, 0);
    // all 9 input timesteps -> channel-last, one dispatch
    tr_cl<false><<<dim3(64, 8, 9), 256, 0, stream>>>(target, xall, 64,
                                                     0, (size_t)10 * 64 * 4096,
                                                     (size_t)64 * 4096, XSTEP);

    top_conv<<<dim3(64, 8), 512, 0, stream>>>(h1A, wtc, btf, zpg, out, 0);

    unsigned short* h0p[2] = { h0A, h0B };
    unsigned short* h1p[2] = { h1A, h1B };
    for (int t = 0; t < 9; ++t) {
        int p = t & 1;
        lstm_conv<64, 128><<<dim3(64, 8), 512, LDS_L0, stream>>>(
            xall + (size_t)t * XSTEP, h0p[p], c0f, wcat0, b0s, zpg, h0p[1 - p], c0f);
        lstm_conv<128, 128><<<dim3(64, 8), 512, LDS_L1, stream>>>(
            h0p[1 - p], h1p[p], c1f, wcat1, b1s, zpg, h1p[1 - p], c1f);
        top_conv<<<dim3(64, 8), 512, 0, stream>>>(h1p[1 - p], wtc, btf, zpg, out, t + 1);
    }
}